// Round 20
// baseline (229.335 us; speedup 1.0000x reference)
//
#include <hip/hip_runtime.h>
#include <math.h>

// Problem constants (B=2, S=2048, D=2048, H=16, hd=128)
#define BATCH 2
#define SEQ   2048
#define DIM   2048
#define NH    16
#define HD    128
#define MTOT  (BATCH*SEQ)
static constexpr float SCALE  = 0.08838834764831845f;            // 1/sqrt(128)
static constexpr float L2E    = 1.4426950408889634f;             // log2(e)
static constexpr float QSCALE = SCALE * L2E;                     // folded into Q
static constexpr float MASKC  = 1.0e9f * L2E;                    // mask in log2 units

// FAITHFUL-RESHAPE LAYOUT: Q[b][h][s][d] = flat[((b*NH+h)*SEQ + s)*HD + d]

typedef short s8  __attribute__((ext_vector_type(8)));   // 8 bf16 (4 VGPR) MFMA A/B frag
typedef float f4  __attribute__((ext_vector_type(4)));   // MFMA C/D frag

// Round-to-nearest-even bf16 helpers.
__device__ inline unsigned short bf_rn(float f) {
    union { float f; unsigned u; } v; v.f = f;
    unsigned r = v.u + 0x7FFFu + ((v.u >> 16) & 1u);
    return (unsigned short)(r >> 16);
}

#define GLL(g, l) __builtin_amdgcn_global_load_lds( \
    (const __attribute__((address_space(1))) void*)(g), \
    (__attribute__((address_space(3))) void*)(l), 16, 0, 0)

// ---------------------------------------------------------------------------
// Pre-pass A: x fp32 -> xh bf16 (RN).
// ---------------------------------------------------------------------------
__global__ __launch_bounds__(256) void convert_x(
    const float* __restrict__ x, unsigned short* __restrict__ xh)
{
    size_t i = ((size_t)blockIdx.x * 256 + threadIdx.x) * 4;
    float4 v = *(const float4*)(x + i);
    float a[4] = {v.x, v.y, v.z, v.w};
    ushort4 h;
    unsigned short* hp = &h.x;
    #pragma unroll
    for (int j = 0; j < 4; ++j) hp[j] = bf_rn(a[j]);
    *(ushort4*)(xh + i) = h;
}

// ---------------------------------------------------------------------------
// Pre-pass B: W [k][n] fp32 -> Wt_hi [n][k] bf16 (RN, hi only).
// ---------------------------------------------------------------------------
__global__ __launch_bounds__(256) void convert_wT(
    const float* __restrict__ Wq, const float* __restrict__ Wk,
    const float* __restrict__ Wv,
    unsigned short* __restrict__ Wth)
{
    const int z = blockIdx.z;
    const float* W = (z == 0) ? Wq : (z == 1) ? Wk : Wv;
    unsigned short* th = Wth + (size_t)z * DIM * DIM;

    __shared__ unsigned short Th[64][72];

    const int k0 = blockIdx.x * 64;
    const int n0 = blockIdx.y * 64;
    const int tid = threadIdx.x;

    #pragma unroll
    for (int i = 0; i < 4; ++i) {
        int idx = tid + i * 256;
        int kk = idx >> 4, n4 = idx & 15;
        float4 w = *(const float4*)(W + (size_t)(k0 + kk) * DIM + n0 + n4 * 4);
        float a[4] = {w.x, w.y, w.z, w.w};
        #pragma unroll
        for (int j = 0; j < 4; ++j)
            Th[n4 * 4 + j][kk] = bf_rn(a[j]);
    }
    __syncthreads();
    #pragma unroll
    for (int i = 0; i < 2; ++i) {
        int idx = tid + i * 256;
        int nn = idx >> 3, c = idx & 7;
        *(uint4*)(th + (size_t)(n0 + nn) * DIM + k0 + c * 8) =
            *(const uint4*)(&Th[nn][c * 8]);
    }
}

// ---------------------------------------------------------------------------
// bf16 MFMA QKV GEMM — ROUND 20: double-buffered LDS, issue-early STAGE,
// ONE barrier per K-step (r10's verified attn transform applied to the GEMM:
// the vmcnt drain at the barrier now lands after a full MFMA phase).
// Math unchanged from r19 (1-product xh @ Wh; Q pre-scaled by SCALE*log2e).
// ---------------------------------------------------------------------------
__global__ __launch_bounds__(256) void qkv_mfma_split(
    const unsigned short* __restrict__ xh,
    const unsigned short* __restrict__ Wth,
    const float* __restrict__ bq, const float* __restrict__ bk,
    const float* __restrict__ bv,
    unsigned short* __restrict__ qh_, unsigned short* __restrict__ kh_,
    unsigned short* __restrict__ vh_)
{
    const int z = blockIdx.z;
    const unsigned short* Bhg = Wth + (size_t)z * DIM * DIM;
    const float* bias = (z == 0) ? bq : (z == 1) ? bk : bv;
    unsigned short* dh = (z == 0) ? qh_ : (z == 1) ? kh_ : vh_;
    const float oscale = (z == 0) ? QSCALE : 1.0f;

    const int bm = blockIdx.x * 128;
    const int bn = blockIdx.y * 128;

    __shared__ unsigned short AhA[128 * 32], AhB[128 * 32];
    __shared__ unsigned short BhA[128 * 32], BhB[128 * 32];

    const int tid = threadIdx.x;
    const int w = tid >> 6, lane = tid & 63;
    const int wr = w >> 1, wc = w & 1;
    const int lr = lane & 15, lg = lane >> 4;

    const int rA0 = bm + (2 * w + 0) * 16 + (lane >> 2);
    const int rA1 = bm + (2 * w + 1) * 16 + (lane >> 2);
    const int rB0 = bn + (2 * w + 0) * 16 + (lane >> 2);
    const int rB1 = bn + (2 * w + 1) * 16 + (lane >> 2);
    const int kin = (lane & 3) * 8;
    const unsigned short* gah0 = xh + (size_t)rA0 * DIM + kin;
    const unsigned short* gah1 = xh + (size_t)rA1 * DIM + kin;
    const unsigned short* gbh0 = Bhg + (size_t)rB0 * DIM + kin;
    const unsigned short* gbh1 = Bhg + (size_t)rB1 * DIM + kin;

    f4 zero4 = {0.f, 0.f, 0.f, 0.f};
    f4 acc[4][4];
    #pragma unroll
    for (int mi = 0; mi < 4; ++mi)
        #pragma unroll
        for (int ni = 0; ni < 4; ++ni) acc[mi][ni] = zero4;

    const int pA = (wr * 64 + lr) * 32 + lg * 8;
    const int pB = (wc * 64 + lr) * 32 + lg * 8;

#define GSTAGE(K0_, AH_, BH_) do {                                           \
        GLL(gah0 + (K0_), &AH_[(2 * w + 0) * 512]);                          \
        GLL(gah1 + (K0_), &AH_[(2 * w + 1) * 512]);                          \
        GLL(gbh0 + (K0_), &BH_[(2 * w + 0) * 512]);                          \
        GLL(gbh1 + (K0_), &BH_[(2 * w + 1) * 512]);                          \
    } while (0)

#define GCOMP(AH_, BH_) do {                                                 \
        s8 fah[4], fbh[4];                                                   \
        _Pragma("unroll")                                                    \
        for (int i = 0; i < 4; ++i) {                                        \
            fah[i] = *(const s8*)(&AH_[pA + i * 512]);                       \
            fbh[i] = *(const s8*)(&BH_[pB + i * 512]);                       \
        }                                                                    \
        _Pragma("unroll")                                                    \
        for (int mi = 0; mi < 4; ++mi)                                       \
            _Pragma("unroll")                                                \
            for (int ni = 0; ni < 4; ++ni)                                   \
                acc[mi][ni] = __builtin_amdgcn_mfma_f32_16x16x32_bf16(       \
                    fah[mi], fbh[ni], acc[mi][ni], 0, 0, 0);                 \
    } while (0)

    // double-buffered main loop: one barrier per K-step, DMA overlapped
    GSTAGE(0, AhA, BhA);
    __syncthreads();
    for (int k0 = 0; k0 < DIM; k0 += 64) {
        GSTAGE(k0 + 32, AhB, BhB);       // lands during compute of A-buf
        GCOMP(AhA, BhA);
        __syncthreads();                 // drains B-buf DMA; A-buf reads done
        if (k0 + 64 < DIM) GSTAGE(k0 + 64, AhA, BhA);
        GCOMP(AhB, BhB);
        __syncthreads();
    }
#undef GSTAGE
#undef GCOMP

    float bv_[4]; int col_[4];
    #pragma unroll
    for (int ni = 0; ni < 4; ++ni) {
        col_[ni] = bn + wc * 64 + ni * 16 + lr;
        bv_[ni] = bias[col_[ni]];
    }
    #pragma unroll
    for (int mi = 0; mi < 4; ++mi)
        #pragma unroll
        for (int ni = 0; ni < 4; ++ni)
            #pragma unroll
            for (int r = 0; r < 4; ++r) {
                int row = bm + wr * 64 + mi * 16 + lg * 4 + r;
                float v = (acc[mi][ni][r] + bv_[ni]) * oscale;
                dh[(size_t)row * DIM + col_[ni]] = bf_rn(v);
            }
}

// ---------------------------------------------------------------------------
// V head-slice [S][128] -> Vt [b][h][d][s]  (hi plane only).
// ---------------------------------------------------------------------------
__global__ __launch_bounds__(256) void transpose_v(
    const unsigned short* __restrict__ vh, unsigned short* __restrict__ vth)
{
    __shared__ unsigned short T[64][72];
    const int s0 = blockIdx.x * 64;
    const int d0 = blockIdx.y * 64;
    const int bh = blockIdx.z;          // b*NH + h
    const int tid = threadIdx.x;
    {
        const int r = tid >> 2, cs = tid & 3;
        size_t g = ((size_t)bh * SEQ + s0 + r) * HD + d0 + cs * 16;
        *(uint4*)(&T[r][cs * 16])     = *(const uint4*)(vh + g);
        *(uint4*)(&T[r][cs * 16 + 8]) = *(const uint4*)(vh + g + 8);
    }
    __syncthreads();
    {
        const int d = tid >> 2, ss = tid & 3;
        unsigned short bh_[16];
        #pragma unroll
        for (int j = 0; j < 16; ++j)
            bh_[j] = T[ss * 16 + j][d];
        size_t t = ((size_t)bh * HD + d0 + d) * SEQ + s0 + ss * 16;
        *(uint4*)(vth + t)     = ((const uint4*)bh_)[0];
        *(uint4*)(vth + t + 8) = ((const uint4*)bh_)[1];
    }
}

// ---------------------------------------------------------------------------
// MFMA flash attention (verified round 19): QBLK=64, 1024 blocks, heavy-first
// order, exp2 softmax, ones-MFMA denominator, defer-max guard, V hi only.
// ---------------------------------------------------------------------------
#define KVBLK 32
#define NT    (SEQ / KVBLK)
#define PSTR  40

__global__ __launch_bounds__(256, 3) void attn_mfma(
    const unsigned short* __restrict__ qh,
    const unsigned short* __restrict__ kh,
    const unsigned short* __restrict__ vth,
    float* __restrict__ out)
{
    __shared__ unsigned short KhA[KVBLK * HD], KhB[KVBLK * HD];
    __shared__ unsigned short VhA[HD * KVBLK], VhB[HD * KVBLK];
    __shared__ unsigned short Ph[4][16 * PSTR];

    // ---- heavy-first bid -> (qb, b, h): qb order 31,0,1,...,30 ----
    const int bid  = blockIdx.x;
    const int slot = bid >> 5;          // 0..31
    const int bhi  = bid & 31;          // (b,h)
    const int qb   = (slot == 0) ? 31 : slot - 1;
    const int h  = bhi & 15;
    const int b  = bhi >> 4;
    const int qs = qb * 64;

    const int tid = threadIdx.x;
    const int w = tid >> 6, lane = tid & 63;
    const int lr = lane & 15, lg = lane >> 4;
    const int q0 = w * 16;              // 4 waves x 16 q-rows

    const size_t hbase = (size_t)(b * NH + h) * SEQ * HD;

    // ---- persistent Q fragment (hi only, pre-scaled): 16 rows/wave ----
    s8 fqh[4];
    #pragma unroll
    for (int k4 = 0; k4 < 4; ++k4) {
        size_t off = hbase + (size_t)(qs + q0 + lr) * HD
                   + (size_t)((k4 * 4 + lg) * 8);
        fqh[k4] = *(const s8*)(qh + off);
    }

    // ones B-fragment for the denominator MFMA
    s8 ones;
    #pragma unroll
    for (int i = 0; i < 8; ++i) ones[i] = (short)0x3F80;   // bf16 1.0

    f4 O[8], Os;
    f4 zero4 = {0.f, 0.f, 0.f, 0.f};
    #pragma unroll
    for (int nj = 0; nj < 8; ++nj) O[nj] = zero4;
    Os = zero4;
    float mrun[4];
    #pragma unroll
    for (int r = 0; r < 4; ++r) mrun[r] = -INFINITY;

    // staging precompute
    const int kr0 = (2 * w + 0) * 4 + (lane >> 4);
    const int kr1 = (2 * w + 1) * 4 + (lane >> 4);
    const int ks  = lane & 15;
    const int vd0 = (2 * w + 0) * 16 + (lane >> 2);
    const int vd1 = (2 * w + 1) * 16 + (lane >> 2);
    const int vs  = lane & 3;
    const size_t kg0 = hbase + (size_t)kr0 * HD + (size_t)((ks ^ (kr0 & 7)) * 8);
    const size_t kg1 = hbase + (size_t)kr1 * HD + (size_t)((ks ^ (kr1 & 7)) * 8);
    const size_t vg0 = hbase + (size_t)vd0 * SEQ + (size_t)((vs ^ (vd0 & 3)) * 8);
    const size_t vg1 = hbase + (size_t)vd1 * SEQ + (size_t)((vs ^ (vd1 & 3)) * 8);

    const int t0 = (qb == 31) ? 0 : qb * 2;   // tile count 64-2qb: always EVEN

#define STAGE(T_, KH_, VH_) do {                                             \
        const size_t koff = (size_t)(T_) * KVBLK * HD;                       \
        const int    loff = (T_) * KVBLK;                                    \
        GLL(kh + kg0 + koff, &KH_[(2 * w + 0) * 512]);                       \
        GLL(kh + kg1 + koff, &KH_[(2 * w + 1) * 512]);                       \
        GLL(vth + vg0 + loff, &VH_[(2 * w + 0) * 512]);                      \
        GLL(vth + vg1 + loff, &VH_[(2 * w + 1) * 512]);                      \
    } while (0)

    auto compute = [&](int t, const unsigned short* KH, const unsigned short* VH) {
        const int l0 = t * KVBLK;

        // ---- QK^T: qh·kh, 1-product (Q pre-scaled by SCALE*log2e) ----
        s8 fkh[2][4];
        #pragma unroll
        for (int nj = 0; nj < 2; ++nj) {
            const int n = nj * 16 + lr;
            #pragma unroll
            for (int k4 = 0; k4 < 4; ++k4) {
                const int sl = (k4 * 4 + lg) ^ (n & 7);
                fkh[nj][k4] = *(const s8*)(&KH[n * HD + sl * 8]);
            }
        }
        f4 sc[2];
        sc[0] = zero4; sc[1] = zero4;
        #pragma unroll
        for (int k4 = 0; k4 < 4; ++k4)
            #pragma unroll
            for (int nj = 0; nj < 2; ++nj)
                sc[nj] = __builtin_amdgcn_mfma_f32_16x16x32_bf16(
                    fqh[k4], fkh[nj][k4], sc[nj], 0, 0, 0);

        // ---- faithful mask (log2 units) ----
        float v0[4], v1[4];
        bool need = false;
        #pragma unroll
        for (int r = 0; r < 4; ++r) {
            const int srow = qs + q0 + lg * 4 + r;
            float a = sc[0][r];
            float c = sc[1][r];
            if (l0 + lr      <= srow) a -= MASKC;
            if (l0 + 16 + lr <= srow) c -= MASKC;
            v0[r] = a; v1[r] = c;
            const float lim = mrun[r] + 11.5f;   // 8 nats in log2 units
            need = need || (a > lim) || (c > lim);
        }

        // ---- rare path: running max grew -> full rowmax + rescale ----
        if (__any(need)) {
            #pragma unroll
            for (int r = 0; r < 4; ++r) {
                float rmax = fmaxf(v0[r], v1[r]);
                #pragma unroll
                for (int m_ = 1; m_ < 16; m_ <<= 1)
                    rmax = fmaxf(rmax, __shfl_xor(rmax, m_, 64));
                const float mnew = fmaxf(mrun[r], rmax);
                const float corr = exp2f(mrun[r] - mnew);
                mrun[r] = mnew;
                #pragma unroll
                for (int nj = 0; nj < 8; ++nj) O[nj][r] *= corr;
                Os[r] *= corr;
            }
        }

        // ---- P = exp2(v - mrun), store bf16 (bounded by 2^11.5) ----
        #pragma unroll
        for (int r = 0; r < 4; ++r) {
            const float p0 = exp2f(v0[r] - mrun[r]);
            const float p1 = exp2f(v1[r] - mrun[r]);
            const int q = lg * 4 + r;
            Ph[w][q * PSTR + lr]      = bf_rn(p0);
            Ph[w][q * PSTR + 16 + lr] = bf_rn(p1);
        }

        // ---- PV (1-product) + denominator via ones-MFMA ----
        s8 fph, fvh[8];
        fph = *(const s8*)(&Ph[w][lr * PSTR + lg * 8]);
        #pragma unroll
        for (int nj = 0; nj < 8; ++nj) {
            const int d = nj * 16 + lr;
            const int sl = lg ^ (d & 3);
            fvh[nj] = *(const s8*)(&VH[d * KVBLK + sl * 8]);
        }
        #pragma unroll
        for (int nj = 0; nj < 8; ++nj)
            O[nj] = __builtin_amdgcn_mfma_f32_16x16x32_bf16(
                fph, fvh[nj], O[nj], 0, 0, 0);
        Os = __builtin_amdgcn_mfma_f32_16x16x32_bf16(fph, ones, Os, 0, 0, 0);
    };

    // ---- double-buffered main loop: one barrier per tile, DMA overlapped ----
    STAGE(t0, KhA, VhA);
    __syncthreads();
    for (int t = t0; t < NT; t += 2) {
        STAGE(t + 1, KhB, VhB);
        compute(t, KhA, VhA);
        __syncthreads();
        if (t + 2 < NT) STAGE(t + 2, KhA, VhA);
        compute(t + 1, KhB, VhB);
        __syncthreads();
    }
#undef STAGE

    // ---- normalize + write (denominator from the ones-MFMA column) ----
    float* op = out + hbase;
    float inv[4];
    #pragma unroll
    for (int r = 0; r < 4; ++r) inv[r] = 1.f / Os[r];
    #pragma unroll
    for (int nj = 0; nj < 8; ++nj)
        #pragma unroll
        for (int r = 0; r < 4; ++r) {
            const int srow = qs + q0 + lg * 4 + r;
            op[(size_t)srow * HD + nj * 16 + lr] = O[nj][r] * inv[r];
        }
}

// ---------------------------------------------------------------------------
// fp32 fallback GEMM + attention (verified round 3) — tiny-workspace path.
// ---------------------------------------------------------------------------
__global__ __launch_bounds__(256) void qkv_gemm(
    const float* __restrict__ x,
    const float* __restrict__ Wq, const float* __restrict__ bq,
    const float* __restrict__ Wk, const float* __restrict__ bk,
    const float* __restrict__ Wv, const float* __restrict__ bv,
    float* __restrict__ Qo, float* __restrict__ Ko, float* __restrict__ Vo)
{
    const int z = blockIdx.z;
    const float* W    = (z == 0) ? Wq : (z == 1) ? Wk : Wv;
    const float* bias = (z == 0) ? bq : (z == 1) ? bk : bv;
    float*       dst  = (z == 0) ? Qo : (z == 1) ? Ko : Vo;

    __shared__ float As[32][64];
    __shared__ float Bs[32][64];

    const int row0 = blockIdx.x * 64;
    const int col0 = blockIdx.y * 64;
    const int tid  = threadIdx.x;
    const int tm   = tid >> 4;
    const int tn   = tid & 15;

    float acc[4][4] = {};

    for (int k0 = 0; k0 < DIM; k0 += 32) {
        #pragma unroll
        for (int i = 0; i < 2; ++i) {
            int f = tid + i * 256;
            int r = f >> 3, c4 = f & 7;
            float4 a = *(const float4*)(x + (size_t)(row0 + r) * DIM + k0 + c4 * 4);
            As[c4 * 4 + 0][r] = a.x;
            As[c4 * 4 + 1][r] = a.y;
            As[c4 * 4 + 2][r] = a.z;
            As[c4 * 4 + 3][r] = a.w;
        }
        #pragma unroll
        for (int i = 0; i < 2; ++i) {
            int f = tid + i * 256;
            int r = f >> 4, c4 = f & 15;
            *(float4*)(&Bs[r][c4 * 4]) =
                *(const float4*)(W + (size_t)(k0 + r) * DIM + col0 + c4 * 4);
        }
        __syncthreads();
        #pragma unroll
        for (int k = 0; k < 32; ++k) {
            float4 a4 = *(const float4*)(&As[k][tm * 4]);
            float4 b4 = *(const float4*)(&Bs[k][tn * 4]);
            float av[4] = {a4.x, a4.y, a4.z, a4.w};
            float bw[4] = {b4.x, b4.y, b4.z, b4.w};
            #pragma unroll
            for (int i = 0; i < 4; ++i)
                #pragma unroll
                for (int j2 = 0; j2 < 4; ++j2)
                    acc[i][j2] += av[i] * bw[j2];
        }
        __syncthreads();
    }

    float4 bb = *(const float4*)(bias + col0 + tn * 4);
    float bsv[4] = {bb.x, bb.y, bb.z, bb.w};
    #pragma unroll
    for (int i = 0; i < 4; ++i) {
        int r = row0 + tm * 4 + i;
        float4 o;
        o.x = acc[i][0] + bsv[0];
        o.y = acc[i][1] + bsv[1];
        o.z = acc[i][2] + bsv[2];
        o.w = acc[i][3] + bsv[3];
        *(float4*)(dst + (size_t)r * DIM + col0 + tn * 4) = o;
    }
}

__global__ __launch_bounds__(256) void attn_kernel(
    const float* Qbuf,
    const float* __restrict__ Kc,
    const float* __restrict__ Vc,
    float* Out)
{
    __shared__ float smem[16384];
    float* QsT = smem;
    float* Ks  = smem + 8192;
    float* Ps  = smem + 8192;

    const int bid = blockIdx.x;
    const int qb  = bid & 31;
    const int h   = (bid >> 5) & 15;
    const int b   = bid >> 9;
    const size_t base = (size_t)b * SEQ * DIM + (size_t)h * SEQ * HD;
    const float* Qp = Qbuf + base;
    const float* Kp = Kc + base;
    const float* Vp = Vc + base;
    float*       Op = Out + base;

    const int tid = threadIdx.x;
    const int tm  = tid >> 4;
    const int tn  = tid & 15;
    const int qs  = qb * 64;

    #pragma unroll
    for (int i = 0; i < 8; ++i) {
        int f = tid + i * 256;
        int r = f >> 5, c4 = f & 31;
        float4 q = *(const float4*)(Qp + (size_t)(qs + r) * HD + c4 * 4);
        QsT[(c4 * 4 + 0) * 64 + r] = q.x;
        QsT[(c4 * 4 + 1) * 64 + r] = q.y;
        QsT[(c4 * 4 + 2) * 64 + r] = q.z;
        QsT[(c4 * 4 + 3) * 64 + r] = q.w;
    }

    float O[4][8] = {};
    float mrun[4], lrun[4];
    #pragma unroll
    for (int i = 0; i < 4; ++i) { mrun[i] = -INFINITY; lrun[i] = 0.f; }

    const int t0 = (qb == 31) ? 0 : qb;

    __syncthreads();

    for (int t = t0; t < 32; ++t) {
        const int l0 = t * 64;

        #pragma unroll
        for (int i = 0; i < 8; ++i) {
            int f = tid + i * 256;
            int r = f >> 5, c4 = f & 31;
            float4 kv = *(const float4*)(Kp + (size_t)(l0 + r) * HD + c4 * 4);
            int sc4 = c4 ^ ((r >> 2) & 7);
            *(float4*)(&Ks[r * 128 + sc4 * 4]) = kv;
        }
        __syncthreads();

        float sc[4][4] = {};
        for (int k4 = 0; k4 < 32; ++k4) {
            const int kb = k4 * 4;
            float qv[4][4];
            #pragma unroll
            for (int kk = 0; kk < 4; ++kk) {
                float4 q = *(const float4*)(&QsT[(kb + kk) * 64 + tm * 4]);
                qv[kk][0] = q.x; qv[kk][1] = q.y; qv[kk][2] = q.z; qv[kk][3] = q.w;
            }
            float kvv[4][4];
            #pragma unroll
            for (int j = 0; j < 4; ++j) {
                const int n = tn * 4 + j;
                float4 kv = *(const float4*)(&Ks[n * 128 + ((k4 ^ (tn & 7)) << 2)]);
                kvv[j][0] = kv.x; kvv[j][1] = kv.y; kvv[j][2] = kv.z; kvv[j][3] = kv.w;
            }
            #pragma unroll
            for (int kk = 0; kk < 4; ++kk)
                #pragma unroll
                for (int i = 0; i < 4; ++i)
                    #pragma unroll
                    for (int j = 0; j < 4; ++j)
                        sc[i][j] += qv[kk][i] * kvv[j][kk];
        }

        #pragma unroll
        for (int i = 0; i < 4; ++i) {
            const int srow = qs + tm * 4 + i;
            #pragma unroll
            for (int j = 0; j < 4; ++j) {
                float v = sc[i][j] * SCALE;
                const int l = l0 + tn * 4 + j;
                if (l <= srow) v -= 1e9f;
                sc[i][j] = v;
            }
        }

        float corr[4], rsum[4];
        #pragma unroll
        for (int i = 0; i < 4; ++i) {
            float rmax = fmaxf(fmaxf(sc[i][0], sc[i][1]), fmaxf(sc[i][2], sc[i][3]));
            #pragma unroll
            for (int off = 1; off < 16; off <<= 1)
                rmax = fmaxf(rmax, __shfl_xor(rmax, off, 64));
            const float mnew = fmaxf(mrun[i], rmax);
            corr[i] = __expf(mrun[i] - mnew);
            mrun[i] = mnew;
            float s = 0.f;
            #pragma unroll
            for (int j = 0; j < 4; ++j) {
                const float p = __expf(sc[i][j] - mnew);
                sc[i][j] = p;
                s += p;
            }
            #pragma unroll
            for (int off = 1; off < 16; off <<= 1)
                s += __shfl_xor(s, off, 64);
            rsum[i] = s;
        }
        #pragma unroll
        for (int i = 0; i < 4; ++i) {
            lrun[i] = lrun[i] * corr[i] + rsum[i];
            #pragma unroll
            for (int d = 0; d < 8; ++d) O[i][d] *= corr[i];
        }

        __syncthreads();

        #pragma unroll
        for (int i = 0; i < 4; ++i) {
            float4 p4 = make_float4(sc[i][0], sc[i][1], sc[i][2], sc[i][3]);
            *(float4*)(&Ps[(tm * 4 + i) * 68 + tn * 4]) = p4;
        }
        __syncthreads();

        for (int n4 = 0; n4 < 16; ++n4) {
            float pa[4][4];
            #pragma unroll
            for (int i = 0; i < 4; ++i) {
                float4 p = *(const float4*)(&Ps[(tm * 4 + i) * 68 + n4 * 4]);
                pa[i][0] = p.x; pa[i][1] = p.y; pa[i][2] = p.z; pa[i][3] = p.w;
            }
            #pragma unroll
            for (int nn = 0; nn < 4; ++nn) {
                const int l = l0 + n4 * 4 + nn;
                const float4 v0 = *(const float4*)(Vp + (size_t)l * HD + tn * 8);
                const float4 v1 = *(const float4*)(Vp + (size_t)l * HD + tn * 8 + 4);
                #pragma unroll
                for (int i = 0; i < 4; ++i) {
                    const float p = pa[i][nn];
                    O[i][0] += p * v0.x; O[i][1] += p * v0.y;
                    O[i][2] += p * v0.z; O[i][3] += p * v0.w;
                    O[i][4] += p * v1.x; O[i][5] += p * v1.y;
                    O[i][6] += p * v1.z; O[i][7] += p * v1.w;
                }
            }
        }
        __syncthreads();
    }

    #pragma unroll
    for (int i = 0; i < 4; ++i) {
        const float inv = 1.f / lrun[i];
        const int r = qs + tm * 4 + i;
        float4 o0 = make_float4(O[i][0] * inv, O[i][1] * inv, O[i][2] * inv, O[i][3] * inv);
        float4 o1 = make_float4(O[i][4] * inv, O[i][5] * inv, O[i][6] * inv, O[i][7] * inv);
        *(float4*)(Op + (size_t)r * HD + tn * 8)     = o0;
        *(float4*)(Op + (size_t)r * HD + tn * 8 + 4) = o1;
    }
}

// ---------------------------------------------------------------------------
extern "C" void kernel_launch(void* const* d_in, const int* in_sizes, int n_in,
                              void* d_out, int out_size, void* d_ws, size_t ws_size,
                              hipStream_t stream) {
    const float* x  = (const float*)d_in[0];
    const float* Wq = (const float*)d_in[1];
    const float* bq = (const float*)d_in[2];
    const float* Wk = (const float*)d_in[3];
    const float* bk = (const float*)d_in[4];
    const float* Wv = (const float*)d_in[5];
    const float* bv = (const float*)d_in[6];

    float* out = (float*)d_out;

    const size_t NM = (size_t)MTOT * DIM;       // 8,388,608
    const size_t DD = (size_t)DIM * DIM;        // 4,194,304

    const size_t NEED2 = NM * 16 + DD * 6;      // ~159 MB (full MFMA path)

    if (ws_size >= NEED2) {
        // ---- full MFMA path (layout unchanged; spare regions kept) ----
        unsigned short* xh  = (unsigned short*)d_ws;     // later reused as vth
        unsigned short* xl  = xh + NM;                   // spare
        unsigned short* Wth = xl + NM;                   // 3 x DD (hi only)
        unsigned short* qh_ = Wth + 3 * DD;
        unsigned short* ql_ = qh_ + NM;                  // spare
        unsigned short* kh_ = ql_ + NM;
        unsigned short* kl_ = kh_ + NM;                  // spare
        unsigned short* vh_ = kl_ + NM;
        unsigned short* vth = xh;   // alias: x plane dead after GEMM

        convert_x<<<dim3((unsigned)(NM / 4 / 256)), 256, 0, stream>>>(x, xh);
        convert_wT<<<dim3(32, 32, 3), 256, 0, stream>>>(Wq, Wk, Wv, Wth);
        qkv_mfma_split<<<dim3(MTOT / 128, DIM / 128, 3), 256, 0, stream>>>(
            xh, Wth, bq, bk, bv, qh_, kh_, vh_);
        transpose_v<<<dim3(SEQ / 64, HD / 64, BATCH * NH), 256, 0, stream>>>(
            vh_, vth);
        attn_mfma<<<dim3(BATCH * NH * (SEQ / 64)), 256, 0, stream>>>(
            qh_, kh_, vth, out);
    } else {
        // ---- fp32 fallback (verified round 3) ----
        float* Kbuf = (float*)d_ws;
        float* Vbuf = Kbuf + NM;
        qkv_gemm<<<dim3(MTOT / 64, DIM / 64, 3), 256, 0, stream>>>(
            x, Wq, bq, Wk, bk, Wv, bv, out, Kbuf, Vbuf);
        attn_kernel<<<dim3(BATCH * NH * (SEQ / 64)), 256, 0, stream>>>(
            out, Kbuf, Vbuf, out);
    }
}

// Round 21
// 218.598 us; speedup vs baseline: 1.0491x; 1.0491x over previous
//
#include <hip/hip_runtime.h>
#include <math.h>

// Problem constants (B=2, S=2048, D=2048, H=16, hd=128)
#define BATCH 2
#define SEQ   2048
#define DIM   2048
#define NH    16
#define HD    128
#define MTOT  (BATCH*SEQ)
static constexpr float SCALE  = 0.08838834764831845f;            // 1/sqrt(128)
static constexpr float L2E    = 1.4426950408889634f;             // log2(e)
static constexpr float QSCALE = SCALE * L2E;                     // folded into Q
static constexpr float MASKC  = 1.0e9f * L2E;                    // mask in log2 units

// FAITHFUL-RESHAPE LAYOUT: Q[b][h][s][d] = flat[((b*NH+h)*SEQ + s)*HD + d]

typedef short s8  __attribute__((ext_vector_type(8)));   // 8 bf16 (4 VGPR) MFMA A/B frag
typedef float f4  __attribute__((ext_vector_type(4)));   // MFMA C/D frag

// Round-to-nearest-even bf16 helpers.
__device__ inline unsigned short bf_rn(float f) {
    union { float f; unsigned u; } v; v.f = f;
    unsigned r = v.u + 0x7FFFu + ((v.u >> 16) & 1u);
    return (unsigned short)(r >> 16);
}

#define GLL(g, l) __builtin_amdgcn_global_load_lds( \
    (const __attribute__((address_space(1))) void*)(g), \
    (__attribute__((address_space(3))) void*)(l), 16, 0, 0)

// ---------------------------------------------------------------------------
// Pre-pass A: x fp32 -> xh bf16 (RN).
// ---------------------------------------------------------------------------
__global__ __launch_bounds__(256) void convert_x(
    const float* __restrict__ x, unsigned short* __restrict__ xh)
{
    size_t i = ((size_t)blockIdx.x * 256 + threadIdx.x) * 4;
    float4 v = *(const float4*)(x + i);
    float a[4] = {v.x, v.y, v.z, v.w};
    ushort4 h;
    unsigned short* hp = &h.x;
    #pragma unroll
    for (int j = 0; j < 4; ++j) hp[j] = bf_rn(a[j]);
    *(ushort4*)(xh + i) = h;
}

// ---------------------------------------------------------------------------
// Pre-pass B: W [k][n] fp32 -> Wt_hi [n][k] bf16 (RN, hi only).
// ---------------------------------------------------------------------------
__global__ __launch_bounds__(256) void convert_wT(
    const float* __restrict__ Wq, const float* __restrict__ Wk,
    const float* __restrict__ Wv,
    unsigned short* __restrict__ Wth)
{
    const int z = blockIdx.z;
    const float* W = (z == 0) ? Wq : (z == 1) ? Wk : Wv;
    unsigned short* th = Wth + (size_t)z * DIM * DIM;

    __shared__ unsigned short Th[64][72];

    const int k0 = blockIdx.x * 64;
    const int n0 = blockIdx.y * 64;
    const int tid = threadIdx.x;

    #pragma unroll
    for (int i = 0; i < 4; ++i) {
        int idx = tid + i * 256;
        int kk = idx >> 4, n4 = idx & 15;
        float4 w = *(const float4*)(W + (size_t)(k0 + kk) * DIM + n0 + n4 * 4);
        float a[4] = {w.x, w.y, w.z, w.w};
        #pragma unroll
        for (int j = 0; j < 4; ++j)
            Th[n4 * 4 + j][kk] = bf_rn(a[j]);
    }
    __syncthreads();
    #pragma unroll
    for (int i = 0; i < 2; ++i) {
        int idx = tid + i * 256;
        int nn = idx >> 3, c = idx & 7;
        *(uint4*)(th + (size_t)(n0 + nn) * DIM + k0 + c * 8) =
            *(const uint4*)(&Th[nn][c * 8]);
    }
}

// ---------------------------------------------------------------------------
// bf16 MFMA QKV GEMM, 1-product: xh @ Wh — verified round 19 (122 us,
// 845 TF eff).  ROUND 21: reverted r20's explicit double-buffer (regressed
// 122->129: implicit wave-overlap at 2.5 blocks/CU already hides the drain;
// matches learn_hip m99/m100).  Q pre-scaled by SCALE*log2e.
// ---------------------------------------------------------------------------
__global__ __launch_bounds__(256) void qkv_mfma_split(
    const unsigned short* __restrict__ xh,
    const unsigned short* __restrict__ Wth,
    const float* __restrict__ bq, const float* __restrict__ bk,
    const float* __restrict__ bv,
    unsigned short* __restrict__ qh_, unsigned short* __restrict__ kh_,
    unsigned short* __restrict__ vh_)
{
    const int z = blockIdx.z;
    const unsigned short* Bhg = Wth + (size_t)z * DIM * DIM;
    const float* bias = (z == 0) ? bq : (z == 1) ? bk : bv;
    unsigned short* dh = (z == 0) ? qh_ : (z == 1) ? kh_ : vh_;
    const float oscale = (z == 0) ? QSCALE : 1.0f;

    const int bm = blockIdx.x * 128;
    const int bn = blockIdx.y * 128;

    __shared__ unsigned short Ah[128 * 32];
    __shared__ unsigned short Bh[128 * 32];

    const int tid = threadIdx.x;
    const int w = tid >> 6, lane = tid & 63;
    const int wr = w >> 1, wc = w & 1;
    const int lr = lane & 15, lg = lane >> 4;

    const int rA0 = bm + (2 * w + 0) * 16 + (lane >> 2);
    const int rA1 = bm + (2 * w + 1) * 16 + (lane >> 2);
    const int rB0 = bn + (2 * w + 0) * 16 + (lane >> 2);
    const int rB1 = bn + (2 * w + 1) * 16 + (lane >> 2);
    const int kin = (lane & 3) * 8;
    const unsigned short* gah0 = xh + (size_t)rA0 * DIM + kin;
    const unsigned short* gah1 = xh + (size_t)rA1 * DIM + kin;
    const unsigned short* gbh0 = Bhg + (size_t)rB0 * DIM + kin;
    const unsigned short* gbh1 = Bhg + (size_t)rB1 * DIM + kin;
    unsigned short* lah0 = &Ah[(2 * w + 0) * 512];
    unsigned short* lah1 = &Ah[(2 * w + 1) * 512];
    unsigned short* lbh0 = &Bh[(2 * w + 0) * 512];
    unsigned short* lbh1 = &Bh[(2 * w + 1) * 512];

    f4 zero4 = {0.f, 0.f, 0.f, 0.f};
    f4 acc[4][4];
    #pragma unroll
    for (int mi = 0; mi < 4; ++mi)
        #pragma unroll
        for (int ni = 0; ni < 4; ++ni) acc[mi][ni] = zero4;

    const unsigned short* pAh = &Ah[(wr * 64 + lr) * 32 + lg * 8];
    const unsigned short* pBh = &Bh[(wc * 64 + lr) * 32 + lg * 8];

    for (int k0 = 0; k0 < DIM; k0 += 32) {
        GLL(gah0 + k0, lah0); GLL(gah1 + k0, lah1);
        GLL(gbh0 + k0, lbh0); GLL(gbh1 + k0, lbh1);
        __syncthreads();

        s8 fah[4], fbh[4];
        #pragma unroll
        for (int i = 0; i < 4; ++i) {
            fah[i] = *(const s8*)(pAh + i * 512);
            fbh[i] = *(const s8*)(pBh + i * 512);
        }
        #pragma unroll
        for (int mi = 0; mi < 4; ++mi)
            #pragma unroll
            for (int ni = 0; ni < 4; ++ni)
                acc[mi][ni] = __builtin_amdgcn_mfma_f32_16x16x32_bf16(
                    fah[mi], fbh[ni], acc[mi][ni], 0, 0, 0);
        __syncthreads();
    }

    float bv_[4]; int col_[4];
    #pragma unroll
    for (int ni = 0; ni < 4; ++ni) {
        col_[ni] = bn + wc * 64 + ni * 16 + lr;
        bv_[ni] = bias[col_[ni]];
    }
    #pragma unroll
    for (int mi = 0; mi < 4; ++mi)
        #pragma unroll
        for (int ni = 0; ni < 4; ++ni)
            #pragma unroll
            for (int r = 0; r < 4; ++r) {
                int row = bm + wr * 64 + mi * 16 + lg * 4 + r;
                float v = (acc[mi][ni][r] + bv_[ni]) * oscale;
                dh[(size_t)row * DIM + col_[ni]] = bf_rn(v);
            }
}

// ---------------------------------------------------------------------------
// V head-slice [S][128] -> Vt [b][h][d][s]  (hi plane only).
// ---------------------------------------------------------------------------
__global__ __launch_bounds__(256) void transpose_v(
    const unsigned short* __restrict__ vh, unsigned short* __restrict__ vth)
{
    __shared__ unsigned short T[64][72];
    const int s0 = blockIdx.x * 64;
    const int d0 = blockIdx.y * 64;
    const int bh = blockIdx.z;          // b*NH + h
    const int tid = threadIdx.x;
    {
        const int r = tid >> 2, cs = tid & 3;
        size_t g = ((size_t)bh * SEQ + s0 + r) * HD + d0 + cs * 16;
        *(uint4*)(&T[r][cs * 16])     = *(const uint4*)(vh + g);
        *(uint4*)(&T[r][cs * 16 + 8]) = *(const uint4*)(vh + g + 8);
    }
    __syncthreads();
    {
        const int d = tid >> 2, ss = tid & 3;
        unsigned short bh_[16];
        #pragma unroll
        for (int j = 0; j < 16; ++j)
            bh_[j] = T[ss * 16 + j][d];
        size_t t = ((size_t)bh * HD + d0 + d) * SEQ + s0 + ss * 16;
        *(uint4*)(vth + t)     = ((const uint4*)bh_)[0];
        *(uint4*)(vth + t + 8) = ((const uint4*)bh_)[1];
    }
}

// ---------------------------------------------------------------------------
// MFMA flash attention (verified round 19): QBLK=64, 1024 blocks, heavy-first
// order, exp2 softmax, ones-MFMA denominator, defer-max guard, V hi only.
// ---------------------------------------------------------------------------
#define KVBLK 32
#define NT    (SEQ / KVBLK)
#define PSTR  40

__global__ __launch_bounds__(256, 3) void attn_mfma(
    const unsigned short* __restrict__ qh,
    const unsigned short* __restrict__ kh,
    const unsigned short* __restrict__ vth,
    float* __restrict__ out)
{
    __shared__ unsigned short KhA[KVBLK * HD], KhB[KVBLK * HD];
    __shared__ unsigned short VhA[HD * KVBLK], VhB[HD * KVBLK];
    __shared__ unsigned short Ph[4][16 * PSTR];

    // ---- heavy-first bid -> (qb, b, h): qb order 31,0,1,...,30 ----
    const int bid  = blockIdx.x;
    const int slot = bid >> 5;          // 0..31
    const int bhi  = bid & 31;          // (b,h)
    const int qb   = (slot == 0) ? 31 : slot - 1;
    const int h  = bhi & 15;
    const int b  = bhi >> 4;
    const int qs = qb * 64;

    const int tid = threadIdx.x;
    const int w = tid >> 6, lane = tid & 63;
    const int lr = lane & 15, lg = lane >> 4;
    const int q0 = w * 16;              // 4 waves x 16 q-rows

    const size_t hbase = (size_t)(b * NH + h) * SEQ * HD;

    // ---- persistent Q fragment (hi only, pre-scaled): 16 rows/wave ----
    s8 fqh[4];
    #pragma unroll
    for (int k4 = 0; k4 < 4; ++k4) {
        size_t off = hbase + (size_t)(qs + q0 + lr) * HD
                   + (size_t)((k4 * 4 + lg) * 8);
        fqh[k4] = *(const s8*)(qh + off);
    }

    // ones B-fragment for the denominator MFMA
    s8 ones;
    #pragma unroll
    for (int i = 0; i < 8; ++i) ones[i] = (short)0x3F80;   // bf16 1.0

    f4 O[8], Os;
    f4 zero4 = {0.f, 0.f, 0.f, 0.f};
    #pragma unroll
    for (int nj = 0; nj < 8; ++nj) O[nj] = zero4;
    Os = zero4;
    float mrun[4];
    #pragma unroll
    for (int r = 0; r < 4; ++r) mrun[r] = -INFINITY;

    // staging precompute
    const int kr0 = (2 * w + 0) * 4 + (lane >> 4);
    const int kr1 = (2 * w + 1) * 4 + (lane >> 4);
    const int ks  = lane & 15;
    const int vd0 = (2 * w + 0) * 16 + (lane >> 2);
    const int vd1 = (2 * w + 1) * 16 + (lane >> 2);
    const int vs  = lane & 3;
    const size_t kg0 = hbase + (size_t)kr0 * HD + (size_t)((ks ^ (kr0 & 7)) * 8);
    const size_t kg1 = hbase + (size_t)kr1 * HD + (size_t)((ks ^ (kr1 & 7)) * 8);
    const size_t vg0 = hbase + (size_t)vd0 * SEQ + (size_t)((vs ^ (vd0 & 3)) * 8);
    const size_t vg1 = hbase + (size_t)vd1 * SEQ + (size_t)((vs ^ (vd1 & 3)) * 8);

    const int t0 = (qb == 31) ? 0 : qb * 2;   // tile count 64-2qb: always EVEN

#define STAGE(T_, KH_, VH_) do {                                             \
        const size_t koff = (size_t)(T_) * KVBLK * HD;                       \
        const int    loff = (T_) * KVBLK;                                    \
        GLL(kh + kg0 + koff, &KH_[(2 * w + 0) * 512]);                       \
        GLL(kh + kg1 + koff, &KH_[(2 * w + 1) * 512]);                       \
        GLL(vth + vg0 + loff, &VH_[(2 * w + 0) * 512]);                      \
        GLL(vth + vg1 + loff, &VH_[(2 * w + 1) * 512]);                      \
    } while (0)

    auto compute = [&](int t, const unsigned short* KH, const unsigned short* VH) {
        const int l0 = t * KVBLK;

        // ---- QK^T: qh·kh, 1-product (Q pre-scaled by SCALE*log2e) ----
        s8 fkh[2][4];
        #pragma unroll
        for (int nj = 0; nj < 2; ++nj) {
            const int n = nj * 16 + lr;
            #pragma unroll
            for (int k4 = 0; k4 < 4; ++k4) {
                const int sl = (k4 * 4 + lg) ^ (n & 7);
                fkh[nj][k4] = *(const s8*)(&KH[n * HD + sl * 8]);
            }
        }
        f4 sc[2];
        sc[0] = zero4; sc[1] = zero4;
        #pragma unroll
        for (int k4 = 0; k4 < 4; ++k4)
            #pragma unroll
            for (int nj = 0; nj < 2; ++nj)
                sc[nj] = __builtin_amdgcn_mfma_f32_16x16x32_bf16(
                    fqh[k4], fkh[nj][k4], sc[nj], 0, 0, 0);

        // ---- faithful mask (log2 units) ----
        float v0[4], v1[4];
        bool need = false;
        #pragma unroll
        for (int r = 0; r < 4; ++r) {
            const int srow = qs + q0 + lg * 4 + r;
            float a = sc[0][r];
            float c = sc[1][r];
            if (l0 + lr      <= srow) a -= MASKC;
            if (l0 + 16 + lr <= srow) c -= MASKC;
            v0[r] = a; v1[r] = c;
            const float lim = mrun[r] + 11.5f;   // 8 nats in log2 units
            need = need || (a > lim) || (c > lim);
        }

        // ---- rare path: running max grew -> full rowmax + rescale ----
        if (__any(need)) {
            #pragma unroll
            for (int r = 0; r < 4; ++r) {
                float rmax = fmaxf(v0[r], v1[r]);
                #pragma unroll
                for (int m_ = 1; m_ < 16; m_ <<= 1)
                    rmax = fmaxf(rmax, __shfl_xor(rmax, m_, 64));
                const float mnew = fmaxf(mrun[r], rmax);
                const float corr = exp2f(mrun[r] - mnew);
                mrun[r] = mnew;
                #pragma unroll
                for (int nj = 0; nj < 8; ++nj) O[nj][r] *= corr;
                Os[r] *= corr;
            }
        }

        // ---- P = exp2(v - mrun), store bf16 (bounded by 2^11.5) ----
        #pragma unroll
        for (int r = 0; r < 4; ++r) {
            const float p0 = exp2f(v0[r] - mrun[r]);
            const float p1 = exp2f(v1[r] - mrun[r]);
            const int q = lg * 4 + r;
            Ph[w][q * PSTR + lr]      = bf_rn(p0);
            Ph[w][q * PSTR + 16 + lr] = bf_rn(p1);
        }

        // ---- PV (1-product) + denominator via ones-MFMA ----
        s8 fph, fvh[8];
        fph = *(const s8*)(&Ph[w][lr * PSTR + lg * 8]);
        #pragma unroll
        for (int nj = 0; nj < 8; ++nj) {
            const int d = nj * 16 + lr;
            const int sl = lg ^ (d & 3);
            fvh[nj] = *(const s8*)(&VH[d * KVBLK + sl * 8]);
        }
        #pragma unroll
        for (int nj = 0; nj < 8; ++nj)
            O[nj] = __builtin_amdgcn_mfma_f32_16x16x32_bf16(
                fph, fvh[nj], O[nj], 0, 0, 0);
        Os = __builtin_amdgcn_mfma_f32_16x16x32_bf16(fph, ones, Os, 0, 0, 0);
    };

    // ---- double-buffered main loop: one barrier per tile, DMA overlapped ----
    STAGE(t0, KhA, VhA);
    __syncthreads();
    for (int t = t0; t < NT; t += 2) {
        STAGE(t + 1, KhB, VhB);
        compute(t, KhA, VhA);
        __syncthreads();
        if (t + 2 < NT) STAGE(t + 2, KhA, VhA);
        compute(t + 1, KhB, VhB);
        __syncthreads();
    }
#undef STAGE

    // ---- normalize + write (denominator from the ones-MFMA column) ----
    float* op = out + hbase;
    float inv[4];
    #pragma unroll
    for (int r = 0; r < 4; ++r) inv[r] = 1.f / Os[r];
    #pragma unroll
    for (int nj = 0; nj < 8; ++nj)
        #pragma unroll
        for (int r = 0; r < 4; ++r) {
            const int srow = qs + q0 + lg * 4 + r;
            op[(size_t)srow * HD + nj * 16 + lr] = O[nj][r] * inv[r];
        }
}

// ---------------------------------------------------------------------------
// fp32 fallback GEMM + attention (verified round 3) — tiny-workspace path.
// ---------------------------------------------------------------------------
__global__ __launch_bounds__(256) void qkv_gemm(
    const float* __restrict__ x,
    const float* __restrict__ Wq, const float* __restrict__ bq,
    const float* __restrict__ Wk, const float* __restrict__ bk,
    const float* __restrict__ Wv, const float* __restrict__ bv,
    float* __restrict__ Qo, float* __restrict__ Ko, float* __restrict__ Vo)
{
    const int z = blockIdx.z;
    const float* W    = (z == 0) ? Wq : (z == 1) ? Wk : Wv;
    const float* bias = (z == 0) ? bq : (z == 1) ? bk : bv;
    float*       dst  = (z == 0) ? Qo : (z == 1) ? Ko : Vo;

    __shared__ float As[32][64];
    __shared__ float Bs[32][64];

    const int row0 = blockIdx.x * 64;
    const int col0 = blockIdx.y * 64;
    const int tid  = threadIdx.x;
    const int tm   = tid >> 4;
    const int tn   = tid & 15;

    float acc[4][4] = {};

    for (int k0 = 0; k0 < DIM; k0 += 32) {
        #pragma unroll
        for (int i = 0; i < 2; ++i) {
            int f = tid + i * 256;
            int r = f >> 3, c4 = f & 7;
            float4 a = *(const float4*)(x + (size_t)(row0 + r) * DIM + k0 + c4 * 4);
            As[c4 * 4 + 0][r] = a.x;
            As[c4 * 4 + 1][r] = a.y;
            As[c4 * 4 + 2][r] = a.z;
            As[c4 * 4 + 3][r] = a.w;
        }
        #pragma unroll
        for (int i = 0; i < 2; ++i) {
            int f = tid + i * 256;
            int r = f >> 4, c4 = f & 15;
            *(float4*)(&Bs[r][c4 * 4]) =
                *(const float4*)(W + (size_t)(k0 + r) * DIM + col0 + c4 * 4);
        }
        __syncthreads();
        #pragma unroll
        for (int k = 0; k < 32; ++k) {
            float4 a4 = *(const float4*)(&As[k][tm * 4]);
            float4 b4 = *(const float4*)(&Bs[k][tn * 4]);
            float av[4] = {a4.x, a4.y, a4.z, a4.w};
            float bw[4] = {b4.x, b4.y, b4.z, b4.w};
            #pragma unroll
            for (int i = 0; i < 4; ++i)
                #pragma unroll
                for (int j2 = 0; j2 < 4; ++j2)
                    acc[i][j2] += av[i] * bw[j2];
        }
        __syncthreads();
    }

    float4 bb = *(const float4*)(bias + col0 + tn * 4);
    float bsv[4] = {bb.x, bb.y, bb.z, bb.w};
    #pragma unroll
    for (int i = 0; i < 4; ++i) {
        int r = row0 + tm * 4 + i;
        float4 o;
        o.x = acc[i][0] + bsv[0];
        o.y = acc[i][1] + bsv[1];
        o.z = acc[i][2] + bsv[2];
        o.w = acc[i][3] + bsv[3];
        *(float4*)(dst + (size_t)r * DIM + col0 + tn * 4) = o;
    }
}

__global__ __launch_bounds__(256) void attn_kernel(
    const float* Qbuf,
    const float* __restrict__ Kc,
    const float* __restrict__ Vc,
    float* Out)
{
    __shared__ float smem[16384];
    float* QsT = smem;
    float* Ks  = smem + 8192;
    float* Ps  = smem + 8192;

    const int bid = blockIdx.x;
    const int qb  = bid & 31;
    const int h   = (bid >> 5) & 15;
    const int b   = bid >> 9;
    const size_t base = (size_t)b * SEQ * DIM + (size_t)h * SEQ * HD;
    const float* Qp = Qbuf + base;
    const float* Kp = Kc + base;
    const float* Vp = Vc + base;
    float*       Op = Out + base;

    const int tid = threadIdx.x;
    const int tm  = tid >> 4;
    const int tn  = tid & 15;
    const int qs  = qb * 64;

    #pragma unroll
    for (int i = 0; i < 8; ++i) {
        int f = tid + i * 256;
        int r = f >> 5, c4 = f & 31;
        float4 q = *(const float4*)(Qp + (size_t)(qs + r) * HD + c4 * 4);
        QsT[(c4 * 4 + 0) * 64 + r] = q.x;
        QsT[(c4 * 4 + 1) * 64 + r] = q.y;
        QsT[(c4 * 4 + 2) * 64 + r] = q.z;
        QsT[(c4 * 4 + 3) * 64 + r] = q.w;
    }

    float O[4][8] = {};
    float mrun[4], lrun[4];
    #pragma unroll
    for (int i = 0; i < 4; ++i) { mrun[i] = -INFINITY; lrun[i] = 0.f; }

    const int t0 = (qb == 31) ? 0 : qb;

    __syncthreads();

    for (int t = t0; t < 32; ++t) {
        const int l0 = t * 64;

        #pragma unroll
        for (int i = 0; i < 8; ++i) {
            int f = tid + i * 256;
            int r = f >> 5, c4 = f & 31;
            float4 kv = *(const float4*)(Kp + (size_t)(l0 + r) * HD + c4 * 4);
            int sc4 = c4 ^ ((r >> 2) & 7);
            *(float4*)(&Ks[r * 128 + sc4 * 4]) = kv;
        }
        __syncthreads();

        float sc[4][4] = {};
        for (int k4 = 0; k4 < 32; ++k4) {
            const int kb = k4 * 4;
            float qv[4][4];
            #pragma unroll
            for (int kk = 0; kk < 4; ++kk) {
                float4 q = *(const float4*)(&QsT[(kb + kk) * 64 + tm * 4]);
                qv[kk][0] = q.x; qv[kk][1] = q.y; qv[kk][2] = q.z; qv[kk][3] = q.w;
            }
            float kvv[4][4];
            #pragma unroll
            for (int j = 0; j < 4; ++j) {
                const int n = tn * 4 + j;
                float4 kv = *(const float4*)(&Ks[n * 128 + ((k4 ^ (tn & 7)) << 2)]);
                kvv[j][0] = kv.x; kvv[j][1] = kv.y; kvv[j][2] = kv.z; kvv[j][3] = kv.w;
            }
            #pragma unroll
            for (int kk = 0; kk < 4; ++kk)
                #pragma unroll
                for (int i = 0; i < 4; ++i)
                    #pragma unroll
                    for (int j = 0; j < 4; ++j)
                        sc[i][j] += qv[kk][i] * kvv[j][kk];
        }

        #pragma unroll
        for (int i = 0; i < 4; ++i) {
            const int srow = qs + tm * 4 + i;
            #pragma unroll
            for (int j = 0; j < 4; ++j) {
                float v = sc[i][j] * SCALE;
                const int l = l0 + tn * 4 + j;
                if (l <= srow) v -= 1e9f;
                sc[i][j] = v;
            }
        }

        float corr[4], rsum[4];
        #pragma unroll
        for (int i = 0; i < 4; ++i) {
            float rmax = fmaxf(fmaxf(sc[i][0], sc[i][1]), fmaxf(sc[i][2], sc[i][3]));
            #pragma unroll
            for (int off = 1; off < 16; off <<= 1)
                rmax = fmaxf(rmax, __shfl_xor(rmax, off, 64));
            const float mnew = fmaxf(mrun[i], rmax);
            corr[i] = __expf(mrun[i] - mnew);
            mrun[i] = mnew;
            float s = 0.f;
            #pragma unroll
            for (int j = 0; j < 4; ++j) {
                const float p = __expf(sc[i][j] - mnew);
                sc[i][j] = p;
                s += p;
            }
            #pragma unroll
            for (int off = 1; off < 16; off <<= 1)
                s += __shfl_xor(s, off, 64);
            rsum[i] = s;
        }
        #pragma unroll
        for (int i = 0; i < 4; ++i) {
            lrun[i] = lrun[i] * corr[i] + rsum[i];
            #pragma unroll
            for (int d = 0; d < 8; ++d) O[i][d] *= corr[i];
        }

        __syncthreads();

        #pragma unroll
        for (int i = 0; i < 4; ++i) {
            float4 p4 = make_float4(sc[i][0], sc[i][1], sc[i][2], sc[i][3]);
            *(float4*)(&Ps[(tm * 4 + i) * 68 + tn * 4]) = p4;
        }
        __syncthreads();

        for (int n4 = 0; n4 < 16; ++n4) {
            float pa[4][4];
            #pragma unroll
            for (int i = 0; i < 4; ++i) {
                float4 p = *(const float4*)(&Ps[(tm * 4 + i) * 68 + n4 * 4]);
                pa[i][0] = p.x; pa[i][1] = p.y; pa[i][2] = p.z; pa[i][3] = p.w;
            }
            #pragma unroll
            for (int nn = 0; nn < 4; ++nn) {
                const int l = l0 + n4 * 4 + nn;
                const float4 v0 = *(const float4*)(Vp + (size_t)l * HD + tn * 8);
                const float4 v1 = *(const float4*)(Vp + (size_t)l * HD + tn * 8 + 4);
                #pragma unroll
                for (int i = 0; i < 4; ++i) {
                    const float p = pa[i][nn];
                    O[i][0] += p * v0.x; O[i][1] += p * v0.y;
                    O[i][2] += p * v0.z; O[i][3] += p * v0.w;
                    O[i][4] += p * v1.x; O[i][5] += p * v1.y;
                    O[i][6] += p * v1.z; O[i][7] += p * v1.w;
                }
            }
        }
        __syncthreads();
    }

    #pragma unroll
    for (int i = 0; i < 4; ++i) {
        const float inv = 1.f / lrun[i];
        const int r = qs + tm * 4 + i;
        float4 o0 = make_float4(O[i][0] * inv, O[i][1] * inv, O[i][2] * inv, O[i][3] * inv);
        float4 o1 = make_float4(O[i][4] * inv, O[i][5] * inv, O[i][6] * inv, O[i][7] * inv);
        *(float4*)(Op + (size_t)r * HD + tn * 8)     = o0;
        *(float4*)(Op + (size_t)r * HD + tn * 8 + 4) = o1;
    }
}

// ---------------------------------------------------------------------------
extern "C" void kernel_launch(void* const* d_in, const int* in_sizes, int n_in,
                              void* d_out, int out_size, void* d_ws, size_t ws_size,
                              hipStream_t stream) {
    const float* x  = (const float*)d_in[0];
    const float* Wq = (const float*)d_in[1];
    const float* bq = (const float*)d_in[2];
    const float* Wk = (const float*)d_in[3];
    const float* bk = (const float*)d_in[4];
    const float* Wv = (const float*)d_in[5];
    const float* bv = (const float*)d_in[6];

    float* out = (float*)d_out;

    const size_t NM = (size_t)MTOT * DIM;       // 8,388,608
    const size_t DD = (size_t)DIM * DIM;        // 4,194,304

    const size_t NEED2 = NM * 16 + DD * 6;      // ~159 MB (full MFMA path)

    if (ws_size >= NEED2) {
        // ---- full MFMA path (layout unchanged; spare regions kept) ----
        unsigned short* xh  = (unsigned short*)d_ws;     // later reused as vth
        unsigned short* xl  = xh + NM;                   // spare
        unsigned short* Wth = xl + NM;                   // 3 x DD (hi only)
        unsigned short* qh_ = Wth + 3 * DD;
        unsigned short* ql_ = qh_ + NM;                  // spare
        unsigned short* kh_ = ql_ + NM;
        unsigned short* kl_ = kh_ + NM;                  // spare
        unsigned short* vh_ = kl_ + NM;
        unsigned short* vth = xh;   // alias: x plane dead after GEMM

        convert_x<<<dim3((unsigned)(NM / 4 / 256)), 256, 0, stream>>>(x, xh);
        convert_wT<<<dim3(32, 32, 3), 256, 0, stream>>>(Wq, Wk, Wv, Wth);
        qkv_mfma_split<<<dim3(MTOT / 128, DIM / 128, 3), 256, 0, stream>>>(
            xh, Wth, bq, bk, bv, qh_, kh_, vh_);
        transpose_v<<<dim3(SEQ / 64, HD / 64, BATCH * NH), 256, 0, stream>>>(
            vh_, vth);
        attn_mfma<<<dim3(BATCH * NH * (SEQ / 64)), 256, 0, stream>>>(
            qh_, kh_, vth, out);
    } else {
        // ---- fp32 fallback (verified round 3) ----
        float* Kbuf = (float*)d_ws;
        float* Vbuf = Kbuf + NM;
        qkv_gemm<<<dim3(MTOT / 64, DIM / 64, 3), 256, 0, stream>>>(
            x, Wq, bq, Wk, bk, Wv, bv, out, Kbuf, Vbuf);
        attn_kernel<<<dim3(BATCH * NH * (SEQ / 64)), 256, 0, stream>>>(
            out, Kbuf, Vbuf, out);
    }
}